// Round 4
// baseline (84.159 us; speedup 1.0000x reference)
//
#include <hip/hip_runtime.h>
#include <cstddef>
#include <cmath>

#define SEQ    1024
#define CH     64
#define UNITS  32
#define WIDTH  64
#define HALFW  32
#define BATCH  4
#define EPS    1e-7f

// ---------------- Kernel 0: xT[b][s][c] = x[b][c][s] ----------------
// 256 blocks (b, 16-s tile) x 256 thr, LDS tile transpose.
#define TSP 16
#define LSP 17
__global__ __launch_bounds__(256) void xT_kernel(
    const float* __restrict__ x, float* __restrict__ xT)
{
    __shared__ float lds[CH * LSP];
    int blk = blockIdx.x;
    int b   = blk >> 6;
    int s0  = (blk & 63) * TSP;
    int tid = threadIdx.x;
    {
        int c = tid >> 2, sq = tid & 3;
        float4 v4 = *reinterpret_cast<const float4*>(
            x + ((size_t)b * CH + c) * SEQ + s0 + 4 * sq);
        lds[c * LSP + 4 * sq + 0] = v4.x;
        lds[c * LSP + 4 * sq + 1] = v4.y;
        lds[c * LSP + 4 * sq + 2] = v4.z;
        lds[c * LSP + 4 * sq + 3] = v4.w;
    }
    __syncthreads();
    {
        int s = tid >> 4, cq = tid & 15;
        float4 v4;
        v4.x = lds[(4 * cq + 0) * LSP + s];
        v4.y = lds[(4 * cq + 1) * LSP + s];
        v4.z = lds[(4 * cq + 2) * LSP + s];
        v4.w = lds[(4 * cq + 3) * LSP + s];
        *reinterpret_cast<float4*>(
            xT + ((size_t)b * SEQ + s0 + s) * CH + 4 * cq) = v4;
    }
}

// ---------------- Kernel 1: q' = x.Wt^T + bh, k = x.Wx^T ------------
// 256 blocks (b, u, s-half) x 128 thr x 4 s. float4 loads, full unroll.
__global__ __launch_bounds__(128) void qk_kernel(
    const float* __restrict__ x, const float* __restrict__ Wt,
    const float* __restrict__ Wx, const float* __restrict__ bh,
    float* __restrict__ q, float* __restrict__ k)
{
    int blk = blockIdx.x;
    int b  = blk >> 6;
    int u  = (blk >> 1) & (UNITS - 1);
    int h  = blk & 1;
    int s4 = h * (SEQ / 2) + (int)threadIdx.x * 4;

    const float* wt = Wt + u * CH;
    const float* wx = Wx + u * CH;
    const float* xb = x + (size_t)b * CH * SEQ + s4;

    float4 qa = {0.f, 0.f, 0.f, 0.f};
    float4 ka = {0.f, 0.f, 0.f, 0.f};
#pragma unroll
    for (int c = 0; c < CH; ++c) {
        float4 xv = *reinterpret_cast<const float4*>(xb + (size_t)c * SEQ);
        float wtc = wt[c], wxc = wx[c];
        qa.x = fmaf(xv.x, wtc, qa.x); qa.y = fmaf(xv.y, wtc, qa.y);
        qa.z = fmaf(xv.z, wtc, qa.z); qa.w = fmaf(xv.w, wtc, qa.w);
        ka.x = fmaf(xv.x, wxc, ka.x); ka.y = fmaf(xv.y, wxc, ka.y);
        ka.z = fmaf(xv.z, wxc, ka.z); ka.w = fmaf(xv.w, wxc, ka.w);
    }
    float bv = bh[u];
    qa.x += bv; qa.y += bv; qa.z += bv; qa.w += bv;
    size_t o = ((size_t)(b * UNITS + u)) * SEQ + s4;
    *reinterpret_cast<float4*>(q + o) = qa;
    *reinterpret_cast<float4*>(k + o) = ka;
}

// ---------------- Kernel 2: one wave per (b,s), barrier-free --------
__global__ __launch_bounds__(64) void attn_kernel(
    const float* __restrict__ xT,
    const float* __restrict__ qp, const float* __restrict__ k,
    const float* __restrict__ Wa_w, const float* __restrict__ Wa_b,
    float* __restrict__ out)
{
    __shared__ __align__(16) float sc[WIDTH];

    int bs   = blockIdx.x;
    int s    = bs & (SEQ - 1);
    int b    = bs >> 10;
    int lane = threadIdx.x;

    int t0 = s - HALFW;
    int t  = t0 + lane;
    bool valid = (t >= 0) && (t < SEQ);
    int tc = t < 0 ? 0 : (t > SEQ - 1 ? SEQ - 1 : t);

    const float* kb = k  + (size_t)b * UNITS * SEQ + tc;   // lane-varying
    const float* qb = qp + (size_t)b * UNITS * SEQ + s;    // wave-uniform

    float e = Wa_b[0];
#pragma unroll
    for (int u = 0; u < UNITS; ++u) {
        float ku = kb[u * SEQ];           // coalesced b32
        float qu = qb[u * SEQ];           // uniform -> s_load
        float wa = Wa_w[u];               // uniform -> s_load
        float z  = qu + ku;
        float ex = __expf(2.f * z);
        float th = 1.f - 2.f * __builtin_amdgcn_rcpf(ex + 1.f);
        e = fmaf(th, wa, e);
    }
    if (!valid) e = -INFINITY;

    float m = e;
#pragma unroll
    for (int off = 32; off >= 1; off >>= 1)
        m = fmaxf(m, __shfl_xor(m, off));
    float p = valid ? __expf(e - m) : 0.f;
    float ssum = p;
#pragma unroll
    for (int off = 32; off >= 1; off >>= 1)
        ssum += __shfl_xor(ssum, off);
    float a = p * __builtin_amdgcn_rcpf(ssum + EPS);

    sc[lane] = a;
    __syncthreads();   // single-wave block: compiles to cheap waitcnt+barrier

    // ---- a-row write: 4 coalesced float4 per lane (full 1024 floats) ----
    float* arow = out + (size_t)BATCH * CH * SEQ + (size_t)bs * SEQ;
#pragma unroll
    for (int qd = 0; qd < 4; ++qd) {
        int i0 = qd * 256 + lane * 4;
        int d  = i0 - t0;
        float4 w4 = {0.f, 0.f, 0.f, 0.f};
        if (d > -4 && d < WIDTH) {
            if (d >= 0     && d     < WIDTH) w4.x = sc[d];
            if (d + 1 >= 0 && d + 1 < WIDTH) w4.y = sc[d + 1];
            if (d + 2 >= 0 && d + 2 < WIDTH) w4.z = sc[d + 2];
            if (d + 3 >= 0 && d + 3 < WIDTH) w4.w = sc[d + 3];
        }
        *reinterpret_cast<float4*>(arow + i0) = w4;
    }

    // ---- v: lane = (jq, cq); 16 aligned b128 xT loads, 2 shuffle levels ----
    int jq = lane >> 4, cq = lane & 15;
    const float* xTb = xT + (size_t)b * SEQ * CH + 4 * cq;
    float4 acc = {0.f, 0.f, 0.f, 0.f};
#pragma unroll
    for (int ii = 0; ii < 4; ++ii) {
        float4 a4 = *reinterpret_cast<const float4*>(&sc[jq * 16 + 4 * ii]);
#pragma unroll
        for (int e2 = 0; e2 < 4; ++e2) {
            int j  = jq * 16 + 4 * ii + e2;
            int tj = t0 + j;
            int tjc = tj < 0 ? 0 : (tj > SEQ - 1 ? SEQ - 1 : tj);
            float4 x4 = *reinterpret_cast<const float4*>(xTb + (size_t)tjc * CH);
            float aj = (e2 == 0) ? a4.x : (e2 == 1) ? a4.y : (e2 == 2) ? a4.z : a4.w;
            acc.x = fmaf(aj, x4.x, acc.x);
            acc.y = fmaf(aj, x4.y, acc.y);
            acc.z = fmaf(aj, x4.z, acc.z);
            acc.w = fmaf(aj, x4.w, acc.w);
        }
    }
    acc.x += __shfl_xor(acc.x, 16); acc.y += __shfl_xor(acc.y, 16);
    acc.z += __shfl_xor(acc.z, 16); acc.w += __shfl_xor(acc.w, 16);
    acc.x += __shfl_xor(acc.x, 32); acc.y += __shfl_xor(acc.y, 32);
    acc.z += __shfl_xor(acc.z, 32); acc.w += __shfl_xor(acc.w, 32);

    if (jq == 0) {
        float* vb = out + ((size_t)b * CH + 4 * cq) * SEQ + s;
        vb[0 * SEQ] = acc.x;
        vb[1 * SEQ] = acc.y;
        vb[2 * SEQ] = acc.z;
        vb[3 * SEQ] = acc.w;
    }
}

extern "C" void kernel_launch(void* const* d_in, const int* in_sizes, int n_in,
                              void* d_out, int out_size, void* d_ws, size_t ws_size,
                              hipStream_t stream) {
    const float* x    = (const float*)d_in[0];
    const float* Wt   = (const float*)d_in[1];
    const float* Wx   = (const float*)d_in[2];
    const float* Wa_w = (const float*)d_in[3];
    const float* Wa_b = (const float*)d_in[4];
    const float* bh   = (const float*)d_in[5];
    float* out = (float*)d_out;

    float* q  = (float*)d_ws;                          // (B,U,S), bh folded
    float* kk = q  + (size_t)BATCH * UNITS * SEQ;      // (B,U,S)
    float* xT = kk + (size_t)BATCH * UNITS * SEQ;      // (B,S,C)

    xT_kernel<<<BATCH * (SEQ / TSP), 256, 0, stream>>>(x, xT);
    qk_kernel<<<BATCH * UNITS * 2, 128, 0, stream>>>(x, Wt, Wx, bh, q, kk);
    attn_kernel<<<BATCH * SEQ, 64, 0, stream>>>(xT, q, kk, Wa_w, Wa_b, out);
}

// Round 5
// 79.810 us; speedup vs baseline: 1.0545x; 1.0545x over previous
//
#include <hip/hip_runtime.h>
#include <cstddef>
#include <cmath>

#define SEQ    1024
#define CH     64
#define UNITS  32
#define WIDTH  64
#define HALFW  32
#define BATCH  4
#define EPS    1e-7f

#define TS     16         // s-rows per block (grid = 4*64 = 256 = #CUs)
#define TT     80         // staged t rows: r+j <= 78
#define XTS    68         // xT stride (words): mult of 4, mod 32 = 4 -> 2-way max
#define KTS    36         // kT/qT stride: mult of 4, mod 32 = 4
#define SCS    68         // sc stride

// ---------------- Kernel 1: q' = x.Wt^T + bh, k = x.Wx^T ------------
__global__ __launch_bounds__(128) void qk_kernel(
    const float* __restrict__ x, const float* __restrict__ Wt,
    const float* __restrict__ Wx, const float* __restrict__ bh,
    float* __restrict__ q, float* __restrict__ k)
{
    int blk = blockIdx.x;
    int b  = blk >> 6;
    int u  = (blk >> 1) & (UNITS - 1);
    int h  = blk & 1;
    int s4 = h * (SEQ / 2) + (int)threadIdx.x * 4;

    const float* wt = Wt + u * CH;
    const float* wx = Wx + u * CH;
    const float* xb = x + (size_t)b * CH * SEQ + s4;

    float4 qa = {0.f, 0.f, 0.f, 0.f};
    float4 ka = {0.f, 0.f, 0.f, 0.f};
#pragma unroll
    for (int c = 0; c < CH; ++c) {
        float4 xv = *reinterpret_cast<const float4*>(xb + (size_t)c * SEQ);
        float wtc = wt[c], wxc = wx[c];
        qa.x = fmaf(xv.x, wtc, qa.x); qa.y = fmaf(xv.y, wtc, qa.y);
        qa.z = fmaf(xv.z, wtc, qa.z); qa.w = fmaf(xv.w, wtc, qa.w);
        ka.x = fmaf(xv.x, wxc, ka.x); ka.y = fmaf(xv.y, wxc, ka.y);
        ka.z = fmaf(xv.z, wxc, ka.z); ka.w = fmaf(xv.w, wxc, ka.w);
    }
    float bv = bh[u];
    qa.x += bv; qa.y += bv; qa.z += bv; qa.w += bv;
    size_t o = ((size_t)(b * UNITS + u)) * SEQ + s4;
    *reinterpret_cast<float4*>(q + o) = qa;
    *reinterpret_cast<float4*>(k + o) = ka;
}

// ---------------- Kernel 2: fused scores/softmax/a-write/v ----------
// One block per (b, 16-s tile): grid 256 = one block per CU.
__global__ __launch_bounds__(256) void attn_kernel(
    const float* __restrict__ x,
    const float* __restrict__ qp, const float* __restrict__ k,
    const float* __restrict__ Wa_w, const float* __restrict__ Wa_b,
    float* __restrict__ out)
{
    __shared__ __align__(16) float xT[TT * XTS];    // xT[tt][c]
    __shared__ __align__(16) float kT[TT * KTS];    // kT[tt][u]
    __shared__ __align__(16) float qT[TS * KTS];    // qT[r][u] (bh folded)
    __shared__ __align__(16) float sc[TS * SCS];    // a[r][j]
    __shared__ __align__(16) float wa_s[UNITS];
    __shared__ float wab_s;

    int tid = threadIdx.x;
    int blk = blockIdx.x;
    int b   = blk >> 6;                 // 64 tiles per batch
    int s0  = (blk & 63) << 4;
    int t0  = s0 - HALFW;

    const float* xb = x  + (size_t)b * CH * SEQ;
    const float* qb = qp + (size_t)b * UNITS * SEQ;
    const float* kb = k  + (size_t)b * UNITS * SEQ;

    // ---- stage xT[tt][c]: 16 cg x 80 tt = 1280 b128 slots, 5/thread ----
#pragma unroll
    for (int i = 0; i < 5; ++i) {
        int idx = i * 256 + tid;
        int cg = idx / TT;
        int tt = idx - cg * TT;
        int t = t0 + tt; t = t < 0 ? 0 : (t > SEQ - 1 ? SEQ - 1 : t);
        float4 v4;
        v4.x = xb[(4 * cg + 0) * SEQ + t];
        v4.y = xb[(4 * cg + 1) * SEQ + t];
        v4.z = xb[(4 * cg + 2) * SEQ + t];
        v4.w = xb[(4 * cg + 3) * SEQ + t];
        *reinterpret_cast<float4*>(&xT[tt * XTS + 4 * cg]) = v4;
    }
    // ---- stage kT[tt][u]: 8 uq x 80 tt = 640 slots ----
#pragma unroll
    for (int i = 0; i < 3; ++i) {
        int idx = i * 256 + tid;
        if (idx < TT * (UNITS / 4)) {
            int uq = idx / TT;
            int tt = idx - uq * TT;
            int t = t0 + tt; t = t < 0 ? 0 : (t > SEQ - 1 ? SEQ - 1 : t);
            float4 v4;
            v4.x = kb[(4 * uq + 0) * SEQ + t];
            v4.y = kb[(4 * uq + 1) * SEQ + t];
            v4.z = kb[(4 * uq + 2) * SEQ + t];
            v4.w = kb[(4 * uq + 3) * SEQ + t];
            *reinterpret_cast<float4*>(&kT[tt * KTS + 4 * uq]) = v4;
        }
    }
    // ---- stage qT[r][u]: 16 r x 8 uq ----
    if (tid < 128) {
        int r = tid >> 3, uq = tid & 7;
        float4 v4;
        v4.x = qb[(4 * uq + 0) * SEQ + s0 + r];
        v4.y = qb[(4 * uq + 1) * SEQ + s0 + r];
        v4.z = qb[(4 * uq + 2) * SEQ + s0 + r];
        v4.w = qb[(4 * uq + 3) * SEQ + s0 + r];
        *reinterpret_cast<float4*>(&qT[r * KTS + 4 * uq]) = v4;
    }
    if (tid < UNITS) wa_s[tid] = Wa_w[tid];
    if (tid == 0)    wab_s = Wa_b[0];
    __syncthreads();

    // ---- scores + softmax (no extra barrier: row = 16 lanes of one wave)
    // thread -> (r = tid>>4, tq = tid&15), j_e = tq + 16e  (strided j so
    // kT row step per lane = 1 -> bank-safe; consecutive-j was 8-way)
    {
        int r = tid >> 4, tq = tid & 15;
        float ev[4] = {wab_s, wab_s, wab_s, wab_s};
#pragma unroll
        for (int uq = 0; uq < 8; ++uq) {
            float4 q4 = *reinterpret_cast<const float4*>(&qT[r * KTS + 4 * uq]);
            float4 w4 = *reinterpret_cast<const float4*>(&wa_s[4 * uq]);
#pragma unroll
            for (int e = 0; e < 4; ++e) {
                float4 k4 = *reinterpret_cast<const float4*>(
                    &kT[(r + tq + 16 * e) * KTS + 4 * uq]);
                float z0 = q4.x + k4.x, z1 = q4.y + k4.y;
                float z2 = q4.z + k4.z, z3 = q4.w + k4.w;
                float a0 = 1.f - 2.f * __builtin_amdgcn_rcpf(__expf(2.f * z0) + 1.f);
                float a1 = 1.f - 2.f * __builtin_amdgcn_rcpf(__expf(2.f * z1) + 1.f);
                float a2 = 1.f - 2.f * __builtin_amdgcn_rcpf(__expf(2.f * z2) + 1.f);
                float a3 = 1.f - 2.f * __builtin_amdgcn_rcpf(__expf(2.f * z3) + 1.f);
                ev[e] += fmaf(a0, w4.x, fmaf(a1, w4.y,
                         fmaf(a2, w4.z, a3 * w4.w)));
            }
        }
#pragma unroll
        for (int e = 0; e < 4; ++e) {
            int t = t0 + r + tq + 16 * e;
            if (t < 0 || t >= SEQ) ev[e] = -INFINITY;
        }
        float m = fmaxf(fmaxf(ev[0], ev[1]), fmaxf(ev[2], ev[3]));
#pragma unroll
        for (int off = 8; off >= 1; off >>= 1) m = fmaxf(m, __shfl_xor(m, off));
        float p0 = __expf(ev[0] - m), p1 = __expf(ev[1] - m);
        float p2 = __expf(ev[2] - m), p3 = __expf(ev[3] - m);
        float ssum = (p0 + p1) + (p2 + p3);
#pragma unroll
        for (int off = 8; off >= 1; off >>= 1) ssum += __shfl_xor(ssum, off);
        float inv = __builtin_amdgcn_rcpf(ssum + EPS);
        sc[r * SCS + tq]      = p0 * inv;
        sc[r * SCS + tq + 16] = p1 * inv;
        sc[r * SCS + tq + 32] = p2 * inv;
        sc[r * SCS + tq + 48] = p3 * inv;
    }
    __syncthreads();

    // ---- a-write first (fire-and-forget; drains under v compute) ----
    // 16 rows x 256 float4 = 4096 slots, 16/thread, coalesced.
    float* abase = out + (size_t)BATCH * CH * SEQ
                       + ((size_t)(b * SEQ + s0)) * SEQ;
#pragma unroll
    for (int i = 0; i < 16; ++i) {
        int slot = i * 256 + tid;
        int row  = slot >> 8;
        int i0   = (slot & 255) << 2;
        int d = i0 - (s0 + row - HALFW);
        float4 w4 = {0.f, 0.f, 0.f, 0.f};
        if (d > -4 && d < WIDTH) {
            const float* srow = &sc[row * SCS];
            if (d >= 0     && d     < WIDTH) w4.x = srow[d];
            if (d + 1 >= 0 && d + 1 < WIDTH) w4.y = srow[d + 1];
            if (d + 2 >= 0 && d + 2 < WIDTH) w4.z = srow[d + 2];
            if (d + 3 >= 0 && d + 3 < WIDTH) w4.w = srow[d + 3];
        }
        *reinterpret_cast<float4*>(&abase[(size_t)row * SEQ + i0]) = w4;
    }

    // ---- v: thread -> (sl = tid&15, cg = tid>>4); 64 b128 xT reads ----
    {
        int sl = tid & 15, cg = tid >> 4;
        float4 acc = {0.f, 0.f, 0.f, 0.f};
        const float* arow = &sc[sl * SCS];
#pragma unroll 16
        for (int j = 0; j < WIDTH; ++j) {
            float a = arow[j];                         // 2-way/broadcast, free
            float4 x4 = *reinterpret_cast<const float4*>(
                &xT[(sl + j) * XTS + 4 * cg]);         // 2-way, free
            acc.x = fmaf(a, x4.x, acc.x);
            acc.y = fmaf(a, x4.y, acc.y);
            acc.z = fmaf(a, x4.z, acc.z);
            acc.w = fmaf(a, x4.w, acc.w);
        }
        float* vb = out + ((size_t)b * CH + 4 * cg) * SEQ + s0 + sl;
        vb[0 * SEQ] = acc.x;
        vb[1 * SEQ] = acc.y;
        vb[2 * SEQ] = acc.z;
        vb[3 * SEQ] = acc.w;
    }
}

extern "C" void kernel_launch(void* const* d_in, const int* in_sizes, int n_in,
                              void* d_out, int out_size, void* d_ws, size_t ws_size,
                              hipStream_t stream) {
    const float* x    = (const float*)d_in[0];
    const float* Wt   = (const float*)d_in[1];
    const float* Wx   = (const float*)d_in[2];
    const float* Wa_w = (const float*)d_in[3];
    const float* Wa_b = (const float*)d_in[4];
    const float* bh   = (const float*)d_in[5];
    float* out = (float*)d_out;

    float* q  = (float*)d_ws;                          // (B,U,S), bh folded
    float* kk = q + (size_t)BATCH * UNITS * SEQ;       // (B,U,S)

    qk_kernel<<<BATCH * UNITS * 2, 128, 0, stream>>>(x, Wt, Wx, bh, q, kk);
    attn_kernel<<<BATCH * (SEQ / TS), 256, 0, stream>>>(x, q, kk, Wa_w, Wa_b, out);
}